// Round 1
// baseline (1475.053 us; speedup 1.0000x reference)
//
#include <hip/hip_runtime.h>
#include <hip/hip_bf16.h>
#include <math.h>

#define B_ 4
#define L_ 2500
#define Y_ 8922
#define VOCAB_ 50002
#define E_ 100
#define F_ 50
#define K_ 9

// ---- workspace layout (float offsets). Total ~9.5 MB. ----
#define WS_CWT   0           // 45000  : conv_w transposed [f][k][e]
#define WS_H     48000       // 500000 : h[b][l][f] fp32
#define WS_DENOM 548000      // 35688  : sum_l exp(s) per (b,y)
#define WS_M     584000      // 1784400: m[b][y][f] (already divided by denom)
#define WS_PART  2369000     // 256    : per-block BCE partials
#define NBLK_FINAL 140

// ---------------- K0: transpose conv_w [F][E][K] -> cwT [F][K][E] ----------------
__global__ __launch_bounds__(256) void k0_cwt(const float* __restrict__ conv_w,
                                              float* __restrict__ cwT) {
    int idx = blockIdx.x * 256 + threadIdx.x;
    if (idx < F_ * E_ * K_) {
        int f = idx / (E_ * K_);
        int r = idx % (E_ * K_);
        int e = r / K_;
        int k = r % K_;
        cwT[f * (E_ * K_) + k * E_ + e] = conv_w[idx];
    }
}

// ---------------- K1: embedding + conv1d(same) + tanh -> h[b][l][f] ----------------
#define LT1 32
__global__ __launch_bounds__(256) void k1_embed_conv(
    const int* __restrict__ x, const float* __restrict__ emb_tab,
    const float* __restrict__ cwT, const float* __restrict__ conv_b,
    float* __restrict__ h) {
    __shared__ __align__(16) float smem[(LT1 + 8) * E_];  // 40 rows x 100, 16 KB
    int b = blockIdx.y;
    int l0 = blockIdx.x * LT1;
    int tid = threadIdx.x;
    // stage embedding rows l0-4 .. l0+35 (zero outside [0,L) and for token==0)
    for (int idx = tid; idx < (LT1 + 8) * E_; idx += 256) {
        int r = idx / E_, e = idx % E_;
        int l = l0 + r - 4;
        float v = 0.f;
        if (l >= 0 && l < L_) {
            int tok = x[b * L_ + l];
            if (tok != 0) v = emb_tab[tok * E_ + e];
        }
        smem[idx] = v;
    }
    __syncthreads();
    const float4* s4 = (const float4*)smem;
    const float4* w4 = (const float4*)cwT;
    for (int idx = tid; idx < LT1 * F_; idx += 256) {
        int ll = idx / F_, f = idx % F_;
        int l = l0 + ll;
        if (l >= L_) continue;
        float acc = conv_b[f];
        for (int k = 0; k < K_; ++k) {
            const float4* se = s4 + (ll + k) * (E_ / 4);
            const float4* we = w4 + f * (E_ * K_ / 4) + k * (E_ / 4);
#pragma unroll
            for (int e4 = 0; e4 < E_ / 4; ++e4) {
                float4 a = se[e4];
                float4 w = we[e4];
                acc += a.x * w.x + a.y * w.y + a.z * w.z + a.w * w.w;
            }
        }
        h[(size_t)(b * L_ + l) * F_ + f] = tanhf(acc);
    }
}

// ---------------- K2: stage 1 — denom[b][y] and m[b][y][f] ----------------
// One WG per (b, 64-y tile). Thread owns one y (ty=tid&63); tl=tid>>6 picks an
// l-quarter of each 64-l tile. U row + m accumulator live in VGPRs; h rows are
// wave-uniform (readfirstlane on tl) -> scalar-broadcast loads, 1 SGPR/VALU op.
__global__ __launch_bounds__(256) void k2_stage1(
    const float* __restrict__ Uw, const float* __restrict__ h,
    float* __restrict__ denom, float* __restrict__ m) {
    int b = blockIdx.y;
    int y0 = blockIdx.x * 64;
    int tid = threadIdx.x;
    int ty = tid & 63;
    int tl = __builtin_amdgcn_readfirstlane(tid >> 6);  // wave-uniform
    int y = y0 + ty;
    bool yv = (y < Y_);

    float u[F_];
#pragma unroll
    for (int f = 0; f < F_; ++f) u[f] = yv ? Uw[(size_t)y * F_ + f] : 0.f;
    float macc[F_];
#pragma unroll
    for (int f = 0; f < F_; ++f) macc[f] = 0.f;
    float dsum = 0.f;

    for (int lt = 0; lt < 40; ++lt) {
        int lbase = lt * 64 + tl * 16;
        for (int j = 0; j < 16; ++j) {
            int l = lbase + j;
            if (l >= L_) break;  // wave-uniform branch
            const float* hr = h + (size_t)(b * L_ + l) * F_;
            float s = 0.f;
#pragma unroll
            for (int f = 0; f < F_; ++f) s += u[f] * hr[f];
            float e = __expf(s);
            dsum += e;
#pragma unroll
            for (int f = 0; f < F_; ++f) macc[f] += e * hr[f];
        }
    }

    // reduce the 4 l-quarters (different waves) via LDS
    __shared__ float dred[4][64];
    __shared__ float mred[4][64][F_];  // 51.2 KB
    __shared__ float dtot[64];
    dred[tl][ty] = dsum;
#pragma unroll
    for (int f = 0; f < F_; ++f) mred[tl][ty][f] = macc[f];
    __syncthreads();
    if (tid < 64) {
        float d = dred[0][tid] + dred[1][tid] + dred[2][tid] + dred[3][tid];
        dtot[tid] = d;
        int yy = y0 + tid;
        if (yy < Y_) denom[(size_t)b * Y_ + yy] = d;
    }
    __syncthreads();
    for (int idx = tid; idx < 64 * F_; idx += 256) {
        int yy = idx / F_, f = idx % F_;
        if (y0 + yy < Y_) {
            float v = mred[0][yy][f] + mred[1][yy][f] + mred[2][yy][f] + mred[3][yy][f];
            m[(size_t)(b * Y_ + y0 + yy) * F_ + f] = v / dtot[yy];
        }
    }
}

// ---------------- K3: stage 2 — recompute scores, write alpha ----------------
// Thread owns one l (h row in VGPRs); loops over a y-chunk with wave-uniform U
// rows. Stores are coalesced over l.
#define YCHUNK 279
__global__ __launch_bounds__(256) void k3_alpha(
    const float* __restrict__ Uw, const float* __restrict__ h,
    const float* __restrict__ denom, float* __restrict__ alpha) {
    int b = blockIdx.z;
    int l = blockIdx.x * 256 + threadIdx.x;
    int ybeg = blockIdx.y * YCHUNK;
    int yend = min(ybeg + YCHUNK, Y_);
    bool lv = (l < L_);
    float hreg[F_];
#pragma unroll
    for (int f = 0; f < F_; ++f) hreg[f] = 0.f;
    if (lv) {
        const float* hr = h + (size_t)(b * L_ + l) * F_;
#pragma unroll
        for (int f = 0; f < F_; ++f) hreg[f] = hr[f];
    }
    float* aout = alpha + (size_t)b * Y_ * L_;
    for (int y = ybeg; y < yend; ++y) {
        const float* ur = Uw + (size_t)y * F_;  // wave-uniform address
        float s = 0.f;
#pragma unroll
        for (int f = 0; f < F_; ++f) s += hreg[f] * ur[f];
        float rd = 1.0f / denom[(size_t)b * Y_ + y];
        float a = __expf(s) * rd;
        if (lv) aout[(size_t)y * L_ + l] = a;
    }
}

// ---------------- K4: y = final_w . m + final_b ; yhat ; BCE partials ----------------
__global__ __launch_bounds__(256) void k4_final(
    const float* __restrict__ m, const float* __restrict__ fw,
    const float* __restrict__ fb, const float* __restrict__ target,
    float* __restrict__ yhat, float* __restrict__ part) {
    int idx = blockIdx.x * 256 + threadIdx.x;
    float term = 0.f;
    if (idx < B_ * Y_) {
        int yy = idx % Y_;
        const float* mr = m + (size_t)idx * F_;
        const float* wr = fw + (size_t)yy * F_;
        float s = fb[yy];
#pragma unroll
        for (int f = 0; f < F_; ++f) s += mr[f] * wr[f];
        yhat[idx] = 1.f / (1.f + __expf(-s));
        float t = target[idx];
        term = fmaxf(s, 0.f) - s * t + log1pf(__expf(-fabsf(s)));
    }
    float v = term;
    for (int off = 32; off > 0; off >>= 1) v += __shfl_down(v, off, 64);
    __shared__ float red[4];
    int lane = threadIdx.x & 63, w = threadIdx.x >> 6;
    if (lane == 0) red[w] = v;
    __syncthreads();
    if (threadIdx.x == 0) part[blockIdx.x] = red[0] + red[1] + red[2] + red[3];
}

// ---------------- K5: reduce partials -> loss ----------------
__global__ __launch_bounds__(256) void k5_loss(const float* __restrict__ part,
                                               float* __restrict__ loss_out) {
    float v = 0.f;
    for (int i = threadIdx.x; i < NBLK_FINAL; i += 256) v += part[i];
    for (int off = 32; off > 0; off >>= 1) v += __shfl_down(v, off, 64);
    __shared__ float red[4];
    int lane = threadIdx.x & 63, w = threadIdx.x >> 6;
    if (lane == 0) red[w] = v;
    __syncthreads();
    if (threadIdx.x == 0) loss_out[0] = (red[0] + red[1] + red[2] + red[3]) / (float)(B_ * Y_);
}

extern "C" void kernel_launch(void* const* d_in, const int* in_sizes, int n_in,
                              void* d_out, int out_size, void* d_ws, size_t ws_size,
                              hipStream_t stream) {
    const int*   x       = (const int*)d_in[0];
    const float* target  = (const float*)d_in[1];
    const float* emb_tab = (const float*)d_in[2];
    const float* conv_w  = (const float*)d_in[3];
    const float* conv_b  = (const float*)d_in[4];
    const float* U_w     = (const float*)d_in[5];
    const float* final_w = (const float*)d_in[6];
    const float* final_b = (const float*)d_in[7];

    float* out = (float*)d_out;
    float* ws  = (float*)d_ws;
    float* cwT   = ws + WS_CWT;
    float* h     = ws + WS_H;
    float* denom = ws + WS_DENOM;
    float* m     = ws + WS_M;
    float* part  = ws + WS_PART;

    float* yhat  = out;                    // [B*Y]
    float* loss  = out + (size_t)B_ * Y_;  // [1]
    float* alpha = loss + 1;               // [B*Y*L]

    k0_cwt<<<(F_ * E_ * K_ + 255) / 256, 256, 0, stream>>>(conv_w, cwT);
    k1_embed_conv<<<dim3((L_ + LT1 - 1) / LT1, B_), 256, 0, stream>>>(x, emb_tab, cwT, conv_b, h);
    k2_stage1<<<dim3((Y_ + 63) / 64, B_), 256, 0, stream>>>(U_w, h, denom, m);
    k3_alpha<<<dim3((L_ + 255) / 256, (Y_ + YCHUNK - 1) / YCHUNK, B_), 256, 0, stream>>>(U_w, h, denom, alpha);
    k4_final<<<NBLK_FINAL, 256, 0, stream>>>(m, final_w, final_b, target, yhat, part);
    k5_loss<<<1, 256, 0, stream>>>(part, loss);
}

// Round 2
// 811.788 us; speedup vs baseline: 1.8170x; 1.8170x over previous
//
#include <hip/hip_runtime.h>
#include <hip/hip_bf16.h>
#include <math.h>

#define B_ 4
#define L_ 2500
#define Y_ 8922
#define E_ 100
#define F_ 50
#define K_ 9

typedef __attribute__((ext_vector_type(8))) short bfrag8;   // 8 bf16 = 4 VGPR
typedef __attribute__((ext_vector_type(4))) float ffrag4;   // 4 fp32 acc

// ---- workspace layout ----
// floats 0..44999            : cwT (conv_w transposed [f][k][e])
// ushort idx 90000..589999   : h bf16 [b][l][f]   (byte 180000, 16B-aligned)
// float idx 295000..2079399  : m [b][y][f] fp32   (byte 1180000)
// float idx 2079400..        : BCE partials
#define WS_CWT_F  0
#define WS_HB_U16 90000
#define WS_M_F    295000
#define WS_PART_F 2079400
#define NBLK_FINAL 140

// ---------------- K0: transpose conv_w [F][E][K] -> cwT [F][K][E] ----------------
__global__ __launch_bounds__(256) void k0_cwt(const float* __restrict__ conv_w,
                                              float* __restrict__ cwT) {
    int idx = blockIdx.x * 256 + threadIdx.x;
    if (idx < F_ * E_ * K_) {
        int f = idx / (E_ * K_);
        int r = idx % (E_ * K_);
        int e = r / K_;
        int k = r % K_;
        cwT[f * (E_ * K_) + k * E_ + e] = conv_w[idx];
    }
}

// ---------------- K1: embedding + conv1d(same) + tanh -> h bf16 [b][l][f] ----------------
#define LT1 32
__global__ __launch_bounds__(256) void k1_embed_conv(
    const int* __restrict__ x, const float* __restrict__ emb_tab,
    const float* __restrict__ cwT, const float* __restrict__ conv_b,
    unsigned short* __restrict__ hb) {
    __shared__ __align__(16) float smem[(LT1 + 8) * E_];  // 40 rows x 100, 16 KB
    int b = blockIdx.y;
    int l0 = blockIdx.x * LT1;
    int tid = threadIdx.x;
    for (int idx = tid; idx < (LT1 + 8) * E_; idx += 256) {
        int r = idx / E_, e = idx % E_;
        int l = l0 + r - 4;
        float v = 0.f;
        if (l >= 0 && l < L_) {
            int tok = x[b * L_ + l];
            if (tok != 0) v = emb_tab[tok * E_ + e];
        }
        smem[idx] = v;
    }
    __syncthreads();
    const float4* s4 = (const float4*)smem;
    const float4* w4 = (const float4*)cwT;
    for (int idx = tid; idx < LT1 * F_; idx += 256) {
        int ll = idx / F_, f = idx % F_;
        int l = l0 + ll;
        if (l >= L_) continue;
        float acc = conv_b[f];
        for (int k = 0; k < K_; ++k) {
            const float4* se = s4 + (ll + k) * (E_ / 4);
            const float4* we = w4 + f * (E_ * K_ / 4) + k * (E_ / 4);
#pragma unroll
            for (int e4 = 0; e4 < E_ / 4; ++e4) {
                float4 a = se[e4];
                float4 w = we[e4];
                acc += a.x * w.x + a.y * w.y + a.z * w.z + a.w * w.w;
            }
        }
        __hip_bfloat16 hv = __float2bfloat16(tanhf(acc));
        hb[(size_t)(b * L_ + l) * F_ + f] = *reinterpret_cast<unsigned short*>(&hv);
    }
}

// ---------------- K2: fused attention (flash-style, no-max softmax) ----------------
// Block: 64 y (4 waves x 16y), loops L in 64-l tiles twice:
//   pass 1: S = U.h^T (MFMA), P = exp(S) -> LDS, PV MFMA accumulates m and
//           (via ones-row at n=50 of h^T) the softmax denominator.
//   pass 2: recompute S, write alpha = exp(S)/denom.
#define YT 64
#define LT 64
#define NLT ((L_ + LT - 1) / LT)   // 40
#define HSTR 72                    // padded LDS leading dim (16B-aligned rows)
__global__ __launch_bounds__(256) void k2_attn(
    const float* __restrict__ Uw, const unsigned short* __restrict__ hb,
    float* __restrict__ m, float* __restrict__ alpha) {
    __shared__ unsigned short hlf[64][HSTR];      // h tile [l][f]   9216 B
    __shared__ unsigned short hfl[64][HSTR];      // h tile [f][l] + ones row 50
    __shared__ unsigned short psh[4][16][HSTR];   // P per wave [y16][l64]

    int b = blockIdx.y;
    int y0 = blockIdx.x * YT;
    int tid = threadIdx.x;
    int wv = tid >> 6;
    int lane = tid & 63;
    int col = lane & 15;
    int quad = lane >> 4;
    int ywb = y0 + wv * 16;
    int ym = ywb + col;   // this lane's A-operand row (y)

    // U A-frags (kept in VGPRs for both passes): A[m=lane&15][k=quad*8+j]
    bfrag8 uf[2];
#pragma unroll
    for (int kc = 0; kc < 2; ++kc) {
#pragma unroll
        for (int j = 0; j < 8; ++j) {
            int f = kc * 32 + quad * 8 + j;
            float v = (ym < Y_ && f < F_) ? Uw[(size_t)ym * F_ + f] : 0.f;
            __hip_bfloat16 bv = __float2bfloat16(v);
            uf[kc][j] = *reinterpret_cast<short*>(&bv);
        }
    }

    // one-time LDS pad init: hlf cols 50..63 = 0; hfl row 50 = 1.0, rows 51..63 = 0
    for (int i = tid; i < 64 * 14; i += 256) {
        int r = i / 14, c = 50 + (i % 14);
        hlf[r][c] = 0;
    }
    for (int i = tid; i < 14 * 64; i += 256) {
        int r = 50 + i / 64, c = i % 64;
        hfl[r][c] = (r == 50) ? (unsigned short)0x3F80 : (unsigned short)0;
    }

    ffrag4 macc[4];
#pragma unroll
    for (int nt = 0; nt < 4; ++nt) macc[nt] = (ffrag4){0.f, 0.f, 0.f, 0.f};

    const unsigned short* hbase = hb + (size_t)b * L_ * F_;

    // ---- pass 1: denom + m ----
    for (int lt = 0; lt < NLT; ++lt) {
        int l0 = lt * LT;
        __syncthreads();   // protect hlf/hfl/psh from previous iteration readers
        const unsigned int* src = (const unsigned int*)(hbase + (size_t)l0 * F_);
        for (int d = tid; d < LT * F_ / 2; d += 256) {   // 1600 dwords
            int r = d / 25, c = d % 25;
            unsigned int v = (l0 + r < L_) ? src[d] : 0u;
            *(unsigned int*)&hlf[r][2 * c] = v;
            hfl[2 * c][r] = (unsigned short)(v & 0xFFFF);
            hfl[2 * c + 1][r] = (unsigned short)(v >> 16);
        }
        __syncthreads();
        // S = U . h^T ; P = exp(S) masked, to LDS
#pragma unroll
        for (int nt = 0; nt < 4; ++nt) {
            ffrag4 s = (ffrag4){0.f, 0.f, 0.f, 0.f};
#pragma unroll
            for (int kc = 0; kc < 2; ++kc) {
                bfrag8 bf = *(const bfrag8*)&hlf[nt * 16 + col][kc * 32 + quad * 8];
                s = __builtin_amdgcn_mfma_f32_16x16x32_bf16(uf[kc], bf, s, 0, 0, 0);
            }
            int l = l0 + nt * 16 + col;
#pragma unroll
            for (int i = 0; i < 4; ++i) {
                float e = (l < L_) ? __expf(s[i]) : 0.f;
                __hip_bfloat16 be = __float2bfloat16(e);
                psh[wv][quad * 4 + i][nt * 16 + col] = *reinterpret_cast<unsigned short*>(&be);
            }
        }
        __syncthreads();   // P visible (cross-lane within wave still needs the fence)
        // m += P . h  (hfl row 50 of ones makes col 50 the denominator)
#pragma unroll
        for (int kc = 0; kc < 2; ++kc) {
            bfrag8 af = *(const bfrag8*)&psh[wv][col][kc * 32 + quad * 8];
#pragma unroll
            for (int nt = 0; nt < 4; ++nt) {
                bfrag8 bf = *(const bfrag8*)&hfl[nt * 16 + col][kc * 32 + quad * 8];
                macc[nt] = __builtin_amdgcn_mfma_f32_16x16x32_bf16(af, bf, macc[nt], 0, 0, 0);
            }
        }
    }

    // denominator lives in C col 50 = n-tile 3, col 2; broadcast within quad
    float rd[4];
#pragma unroll
    for (int i = 0; i < 4; ++i) {
        float d = __shfl(macc[3][i], quad * 16 + 2, 64);
        rd[i] = 1.0f / d;
    }
    // write normalized m
#pragma unroll
    for (int nt = 0; nt < 4; ++nt) {
        int f = nt * 16 + col;
        if (f < F_) {
#pragma unroll
            for (int i = 0; i < 4; ++i) {
                int y = ywb + quad * 4 + i;
                if (y < Y_) m[((size_t)b * Y_ + y) * F_ + f] = macc[nt][i] * rd[i];
            }
        }
    }

    // ---- pass 2: alpha = exp(S)/denom ----
    float* aout = alpha + (size_t)b * Y_ * L_;
    for (int lt = 0; lt < NLT; ++lt) {
        int l0 = lt * LT;
        __syncthreads();
        const unsigned int* src = (const unsigned int*)(hbase + (size_t)l0 * F_);
        for (int d = tid; d < LT * F_ / 2; d += 256) {
            int r = d / 25, c = d % 25;
            unsigned int v = (l0 + r < L_) ? src[d] : 0u;
            *(unsigned int*)&hlf[r][2 * c] = v;
        }
        __syncthreads();
#pragma unroll
        for (int nt = 0; nt < 4; ++nt) {
            ffrag4 s = (ffrag4){0.f, 0.f, 0.f, 0.f};
#pragma unroll
            for (int kc = 0; kc < 2; ++kc) {
                bfrag8 bf = *(const bfrag8*)&hlf[nt * 16 + col][kc * 32 + quad * 8];
                s = __builtin_amdgcn_mfma_f32_16x16x32_bf16(uf[kc], bf, s, 0, 0, 0);
            }
            int l = l0 + nt * 16 + col;
            if (l < L_) {
#pragma unroll
                for (int i = 0; i < 4; ++i) {
                    int y = ywb + quad * 4 + i;
                    if (y < Y_) aout[(size_t)y * L_ + l] = __expf(s[i]) * rd[i];
                }
            }
        }
    }
}

// ---------------- K4: y = final_w . m + final_b ; yhat ; BCE partials ----------------
__global__ __launch_bounds__(256) void k4_final(
    const float* __restrict__ m, const float* __restrict__ fw,
    const float* __restrict__ fb, const float* __restrict__ target,
    float* __restrict__ yhat, float* __restrict__ part) {
    int idx = blockIdx.x * 256 + threadIdx.x;
    float term = 0.f;
    if (idx < B_ * Y_) {
        int yy = idx % Y_;
        const float* mr = m + (size_t)idx * F_;
        const float* wr = fw + (size_t)yy * F_;
        float s = fb[yy];
#pragma unroll
        for (int f = 0; f < F_; ++f) s += mr[f] * wr[f];
        yhat[idx] = 1.f / (1.f + __expf(-s));
        float t = target[idx];
        term = fmaxf(s, 0.f) - s * t + log1pf(__expf(-fabsf(s)));
    }
    float v = term;
    for (int off = 32; off > 0; off >>= 1) v += __shfl_down(v, off, 64);
    __shared__ float red[4];
    int lane = threadIdx.x & 63, w = threadIdx.x >> 6;
    if (lane == 0) red[w] = v;
    __syncthreads();
    if (threadIdx.x == 0) part[blockIdx.x] = red[0] + red[1] + red[2] + red[3];
}

// ---------------- K5: reduce partials -> loss ----------------
__global__ __launch_bounds__(256) void k5_loss(const float* __restrict__ part,
                                               float* __restrict__ loss_out) {
    float v = 0.f;
    for (int i = threadIdx.x; i < NBLK_FINAL; i += 256) v += part[i];
    for (int off = 32; off > 0; off >>= 1) v += __shfl_down(v, off, 64);
    __shared__ float red[4];
    int lane = threadIdx.x & 63, w = threadIdx.x >> 6;
    if (lane == 0) red[w] = v;
    __syncthreads();
    if (threadIdx.x == 0) loss_out[0] = (red[0] + red[1] + red[2] + red[3]) / (float)(B_ * Y_);
}

extern "C" void kernel_launch(void* const* d_in, const int* in_sizes, int n_in,
                              void* d_out, int out_size, void* d_ws, size_t ws_size,
                              hipStream_t stream) {
    const int*   x       = (const int*)d_in[0];
    const float* target  = (const float*)d_in[1];
    const float* emb_tab = (const float*)d_in[2];
    const float* conv_w  = (const float*)d_in[3];
    const float* conv_b  = (const float*)d_in[4];
    const float* U_w     = (const float*)d_in[5];
    const float* final_w = (const float*)d_in[6];
    const float* final_b = (const float*)d_in[7];

    float* out = (float*)d_out;
    float* wsf = (float*)d_ws;
    unsigned short* wsu = (unsigned short*)d_ws;

    float* cwT            = wsf + WS_CWT_F;
    unsigned short* hbf   = wsu + WS_HB_U16;
    float* mbuf           = wsf + WS_M_F;
    float* part           = wsf + WS_PART_F;

    float* yhat  = out;                    // [B*Y]
    float* loss  = out + (size_t)B_ * Y_;  // [1]
    float* alpha = loss + 1;               // [B*Y*L]

    k0_cwt<<<(F_ * E_ * K_ + 255) / 256, 256, 0, stream>>>(conv_w, cwT);
    k1_embed_conv<<<dim3((L_ + LT1 - 1) / LT1, B_), 256, 0, stream>>>(x, emb_tab, cwT, conv_b, hbf);
    k2_attn<<<dim3((Y_ + YT - 1) / YT, B_), 256, 0, stream>>>(U_w, hbf, mbuf, alpha);
    k4_final<<<NBLK_FINAL, 256, 0, stream>>>(mbuf, final_w, final_b, target, yhat, part);
    k5_loss<<<1, 256, 0, stream>>>(part, loss);
}